// Round 1
// baseline (1006.306 us; speedup 1.0000x reference)
//
#include <hip/hip_runtime.h>
#include <hip/hip_bf16.h>
#include <math.h>

#define U_DIM 8192
#define P_DIM 4096
#define D_DIM 64
#define B_DIM 1024
#define H_DIM 50
#define EPSV  1e-8f

typedef __attribute__((ext_vector_type(8))) short short8;
typedef __attribute__((ext_vector_type(4))) float f32x4;

struct APtrs { const float* p[5]; };

__device__ inline unsigned short f2bf(float f) {
    unsigned int u = __float_as_uint(f);
    u += 0x7FFFu + ((u >> 16) & 1u);
    return (unsigned short)(u >> 16);
}

// C[M x 64] += op(A) @ B   (fp32 in, bf16 MFMA, fp32 atomic accumulate)
// TRANS=0: A[m][k] = Ag[m*K + k]
// TRANS=1: A[m][k] = Ag[k*ldm + m]
// Batched over blockIdx.y (r), split-K over blockIdx.z.
template<bool TRANS>
__global__ __launch_bounds__(256) void gemm_n64(
    APtrs Aps, const float* Bmat, float* C,
    int M, int K, int ldm, long strideB, long strideC, int kseg)
{
    const int tid  = threadIdx.x;
    const int wid  = tid >> 6;
    const int lane = tid & 63;
    const int m0   = blockIdx.x * 128;
    const float* Ag = Aps.p[blockIdx.y];
    const float* Bp = Bmat + (size_t)blockIdx.y * strideB;
    float*       Cp = C    + (size_t)blockIdx.y * strideC;
    const int k_begin = blockIdx.z * kseg;
    const int k_end   = k_begin + kseg;

    __shared__ __align__(16) unsigned short a_s[128][40];
    __shared__ __align__(16) unsigned short b_s[64][40];

    f32x4 acc[2][4] = {};

    for (int kk = k_begin; kk < k_end; kk += 32) {
        // ---- stage A tile (128 rows x 32 k) as bf16 ----
        if (!TRANS) {
            int row   = tid >> 1;
            int halfo = (tid & 1) << 4;
            const float* src = Ag + (size_t)(m0 + row) * K + kk + halfo;
            float4 v0 = ((const float4*)src)[0];
            float4 v1 = ((const float4*)src)[1];
            float4 v2 = ((const float4*)src)[2];
            float4 v3 = ((const float4*)src)[3];
            unsigned short* d = &a_s[row][halfo];
            d[0]=f2bf(v0.x); d[1]=f2bf(v0.y); d[2]=f2bf(v0.z); d[3]=f2bf(v0.w);
            d[4]=f2bf(v1.x); d[5]=f2bf(v1.y); d[6]=f2bf(v1.z); d[7]=f2bf(v1.w);
            d[8]=f2bf(v2.x); d[9]=f2bf(v2.y); d[10]=f2bf(v2.z); d[11]=f2bf(v2.w);
            d[12]=f2bf(v3.x); d[13]=f2bf(v3.y); d[14]=f2bf(v3.z); d[15]=f2bf(v3.w);
        } else {
            int krow = tid >> 3;
            int seg  = (tid & 7) << 4;
            const float* src = Ag + (size_t)(kk + krow) * ldm + m0 + seg;
            float4 v0 = ((const float4*)src)[0];
            float4 v1 = ((const float4*)src)[1];
            float4 v2 = ((const float4*)src)[2];
            float4 v3 = ((const float4*)src)[3];
            a_s[seg+ 0][krow]=f2bf(v0.x); a_s[seg+ 1][krow]=f2bf(v0.y);
            a_s[seg+ 2][krow]=f2bf(v0.z); a_s[seg+ 3][krow]=f2bf(v0.w);
            a_s[seg+ 4][krow]=f2bf(v1.x); a_s[seg+ 5][krow]=f2bf(v1.y);
            a_s[seg+ 6][krow]=f2bf(v1.z); a_s[seg+ 7][krow]=f2bf(v1.w);
            a_s[seg+ 8][krow]=f2bf(v2.x); a_s[seg+ 9][krow]=f2bf(v2.y);
            a_s[seg+10][krow]=f2bf(v2.z); a_s[seg+11][krow]=f2bf(v2.w);
            a_s[seg+12][krow]=f2bf(v3.x); a_s[seg+13][krow]=f2bf(v3.y);
            a_s[seg+14][krow]=f2bf(v3.z); a_s[seg+15][krow]=f2bf(v3.w);
        }
        // ---- stage B tile (32 k x 64 n) as bf16, transposed to [n][k] ----
        {
            int krow = tid >> 3;
            int nseg = (tid & 7) << 3;
            const float* src = Bp + ((size_t)(kk + krow) << 6) + nseg;
            float4 v0 = ((const float4*)src)[0];
            float4 v1 = ((const float4*)src)[1];
            b_s[nseg+0][krow]=f2bf(v0.x); b_s[nseg+1][krow]=f2bf(v0.y);
            b_s[nseg+2][krow]=f2bf(v0.z); b_s[nseg+3][krow]=f2bf(v0.w);
            b_s[nseg+4][krow]=f2bf(v1.x); b_s[nseg+5][krow]=f2bf(v1.y);
            b_s[nseg+6][krow]=f2bf(v1.z); b_s[nseg+7][krow]=f2bf(v1.w);
        }
        __syncthreads();

        // ---- MFMA: wave computes 32 rows x 64 cols ----
        const int ko   = (lane >> 4) << 3;
        const int mrow = (wid << 5) + (lane & 15);
        short8 af0 = *(const short8*)&a_s[mrow][ko];
        short8 af1 = *(const short8*)&a_s[mrow + 16][ko];
#pragma unroll
        for (int nt = 0; nt < 4; ++nt) {
            short8 bf = *(const short8*)&b_s[(nt << 4) + (lane & 15)][ko];
            acc[0][nt] = __builtin_amdgcn_mfma_f32_16x16x32_bf16(af0, bf, acc[0][nt], 0, 0, 0);
            acc[1][nt] = __builtin_amdgcn_mfma_f32_16x16x32_bf16(af1, bf, acc[1][nt], 0, 0, 0);
        }
        __syncthreads();
    }

    // ---- epilogue: atomic accumulate (C pre-zeroed; split-K partial sums) ----
    const int col   = lane & 15;
    const int rbase = (lane >> 4) << 2;
#pragma unroll
    for (int mt = 0; mt < 2; ++mt)
#pragma unroll
        for (int nt = 0; nt < 4; ++nt)
#pragma unroll
            for (int i = 0; i < 4; ++i) {
                int row = m0 + (wid << 5) + (mt << 4) + rbase + i;
                atomicAdd(&Cp[((size_t)row << 6) + (nt << 4) + col], acc[mt][nt][i]);
            }
}

__device__ inline float wsum(float v) {
#pragma unroll
    for (int off = 32; off > 0; off >>= 1) v += __shfl_xor(v, off, 64);
    return v;
}

// One wave per user: Xu, cosine sims vs base, mask/var, user_embedding.
__global__ __launch_bounds__(256) void user_stats_k(
    const float* __restrict__ u0, const float* __restrict__ u1,
    const float* __restrict__ u2, const float* __restrict__ W,
    float* __restrict__ base_o, float* __restrict__ var_o, float* __restrict__ ue_o)
{
    int u    = blockIdx.x * 4 + (threadIdx.x >> 6);
    int lane = threadIdx.x & 63;
    size_t ud = ((size_t)u << 6) + lane;

    float b0 = u0[ud];
    float xu[5];
#pragma unroll
    for (int r = 0; r < 5; ++r)
        xu[r] = (b0 + u1[(size_t)r * U_DIM * 64 + ud] + u2[(size_t)r * U_DIM * 64 + ud]) * (1.0f / 3.0f);

    float base = xu[0];
    float n0 = sqrtf(wsum(base * base));
    float sim[4];
#pragma unroll
    for (int a = 0; a < 4; ++a) {
        float d  = wsum(base * xu[a + 1]);
        float nr = sqrtf(wsum(xu[a + 1] * xu[a + 1]));
        sim[a] = d / fmaxf(n0 * nr, EPSV);
    }
    float smax = fmaxf(fmaxf(sim[0], sim[1]), fmaxf(sim[2], sim[3]));
    float ssum = 0.0f;
    float simm[4];
#pragma unroll
    for (int a = 0; a < 4; ++a) { simm[a] = (sim[a] == smax) ? sim[a] : 0.0f; ssum += simm[a]; }
    float mean = ssum * 0.25f;
    float vs = 0.0f;
#pragma unroll
    for (int a = 0; a < 4; ++a) { float t = simm[a] - mean; vs += t * t; }
    vs *= (1.0f / 3.0f);
    float var = logf(sqrtf(vs) + 1.0f);

    float ue = 0.0f;
#pragma unroll
    for (int a = 0; a < 4; ++a) ue += W[((size_t)u << 2) + a] * xu[a + 1];

    base_o[ud] = base;
    ue_o[ud]   = ue;
    if (lane == 0) var_o[u] = var;
}

// One wave per batch element: X_post, X_var_user, AugUser, X_mean_user.
__global__ __launch_bounds__(256) void gather_k(
    const float* __restrict__ p0, const float* __restrict__ p1r0, const float* __restrict__ p2,
    const float* __restrict__ base, const float* __restrict__ var, const float* __restrict__ ue,
    const int* __restrict__ src_id, const int* __restrict__ rumer, float* __restrict__ out)
{
    int b    = blockIdx.x * 4 + (threadIdx.x >> 6);
    int lane = threadIdx.x & 63;

    int sp = src_id[b];
    size_t spd = ((size_t)sp << 6) + lane;
    out[((size_t)b << 6) + lane] = (p0[spd] + p1r0[spd] + p2[spd]) * (1.0f / 3.0f);

    float xv = 0.0f, xm = 0.0f, au = 0.0f;
    for (int h = 0; h < H_DIM; ++h) {
        int uu = rumer[b * H_DIM + h];
        size_t uud = ((size_t)uu << 6) + lane;
        float bv = base[uud];
        xv += var[uu] * bv;
        xm += bv;
        au += ue[uud];
    }
    out[((size_t)(B_DIM     + b) << 6) + lane] = xv;
    out[((size_t)(2 * B_DIM + b) << 6) + lane] = au * (1.0f / H_DIM);
    out[((size_t)(3 * B_DIM + b) << 6) + lane] = xm * (1.0f / H_DIM);
}

extern "C" void kernel_launch(void* const* d_in, const int* in_sizes, int n_in,
                              void* d_out, int out_size, void* d_ws, size_t ws_size,
                              hipStream_t stream)
{
    const float* u0 = (const float*)d_in[5];
    const float* p0 = (const float*)d_in[6];
    const float* W  = (const float*)d_in[7];
    const int* src   = (const int*)d_in[8];
    const int* rumer = (const int*)d_in[10];
    float* out = (float*)d_out;

    APtrs Ap;
    for (int r = 0; r < 5; ++r) Ap.p[r] = (const float*)d_in[r];

    // workspace layout (fp32)
    float* u1   = (float*)d_ws;                 // 5*U*64
    float* p1   = u1 + 5l * U_DIM * 64;         // 5*P*64
    float* p2   = p1 + 5l * P_DIM * 64;         // P*64
    float* u2   = p2 + (long)P_DIM * 64;        // 5*U*64
    float* base = u2 + 5l * U_DIM * 64;         // U*64
    float* var  = base + (long)U_DIM * 64;      // U
    float* ue   = var + U_DIM;                  // U*64

    size_t zero_bytes = (size_t)(5l * U_DIM * 64 + 5l * P_DIM * 64 + (long)P_DIM * 64 + 5l * U_DIM * 64) * sizeof(float);
    hipMemsetAsync(d_ws, 0, zero_bytes, stream);

    // u1[r] = A[r] @ p0
    gemm_n64<false><<<dim3(64, 5, 2), 256, 0, stream>>>(Ap, p0, u1, U_DIM, P_DIM, 0, 0, (long)U_DIM * 64, 2048);
    // p1[r] = A[r]^T @ u0
    gemm_n64<true ><<<dim3(32, 5, 4), 256, 0, stream>>>(Ap, u0, p1, P_DIM, U_DIM, P_DIM, 0, (long)P_DIM * 64, 2048);
    // u2[r] = A[r] @ p1[r]
    gemm_n64<false><<<dim3(64, 5, 2), 256, 0, stream>>>(Ap, p1, u2, U_DIM, P_DIM, 0, (long)P_DIM * 64, (long)U_DIM * 64, 2048);
    // p2[0] = A[0]^T @ u1[0]
    gemm_n64<true ><<<dim3(32, 1, 8), 256, 0, stream>>>(Ap, u1, p2, P_DIM, U_DIM, P_DIM, 0, 0, 1024);

    user_stats_k<<<U_DIM / 4, 256, 0, stream>>>(u0, u1, u2, W, base, var, ue);
    gather_k<<<B_DIM / 4, 256, 0, stream>>>(p0, p1, p2, base, var, ue, src, rumer, out);
}

// Round 2
// 889.170 us; speedup vs baseline: 1.1317x; 1.1317x over previous
//
#include <hip/hip_runtime.h>
#include <hip/hip_bf16.h>
#include <math.h>

#define U_DIM 8192
#define P_DIM 4096
#define B_DIM 1024
#define H_DIM 50
#define EPSV  1e-8f

typedef __attribute__((ext_vector_type(8))) short short8;
typedef __attribute__((ext_vector_type(4))) short short4v;
typedef __attribute__((ext_vector_type(2))) short short2v;
typedef __attribute__((ext_vector_type(4))) float f32x4;

// Skewed LDS row offset (in shorts): stride 40 + 8 extra per 8 rows.
// Keeps every row 16B-aligned (multiple of 8 shorts) while making rows
// 8 apart differ by 4 banks (40*8+8 = 328 shorts = 164 banks = 4 mod 32).
#define AROW(m) ((m) * 40 + ((m) & ~7))

struct APtrs { const float* p[5]; };

__device__ inline unsigned short f2bf(float f) {
    unsigned int u = __float_as_uint(f);
    u += 0x7FFFu + ((u >> 16) & 1u);
    return (unsigned short)(u >> 16);
}

// C[M x 64] += op(A) @ B   (fp32 in, bf16 MFMA, fp32 atomic accumulate)
// TRANS=0: A[m][k] = Ag[m*K + k]        (contraction over columns)
// TRANS=1: A[m][k] = Ag[k*ldm + m]      (contraction over rows)
// Batched over blockIdx.y (r), split-K over blockIdx.z.
template<bool TRANS>
__global__ __launch_bounds__(256, 4) void gemm_n64(
    APtrs Aps, const float* Bmat, float* C,
    int K, int ldm, long strideB, long strideC, int kseg)
{
    const int tid  = threadIdx.x;
    const int wid  = tid >> 6;
    const int lane = tid & 63;
    const int m0   = blockIdx.x * 128;
    const float* Ag = Aps.p[blockIdx.y];
    const float* Bp = Bmat + (size_t)blockIdx.y * strideB;
    float*       Cp = C    + (size_t)blockIdx.y * strideC;
    const int k_begin = blockIdx.z * kseg;

    __shared__ __align__(16) unsigned short a_s[128 * 41];
    __shared__ __align__(16) unsigned short b_s[64 * 41];

    // ---- global source pointers (advance by 32 k per iter) ----
    const float* ap;
    if (!TRANS) ap = Ag + (size_t)(m0 + (tid >> 1)) * K + k_begin + ((tid & 1) << 4);
    else        ap = Ag + (size_t)(k_begin + ((tid >> 5) << 2)) * ldm + m0 + ((tid & 31) << 2);
    const float* bp = Bp + ((size_t)(k_begin + ((tid >> 4) << 1)) << 6) + ((tid & 15) << 2);

    float4 ra[4], rb[2];
    // ---- prologue loads ----
    if (!TRANS) {
#pragma unroll
        for (int j = 0; j < 4; ++j) ra[j] = ((const float4*)ap)[j];
    } else {
#pragma unroll
        for (int j = 0; j < 4; ++j) ra[j] = *(const float4*)(ap + (size_t)j * ldm);
    }
    rb[0] = *(const float4*)bp;
    rb[1] = *(const float4*)(bp + 64);

    f32x4 acc[2][4] = {};
    const int iters = kseg >> 5;

    for (int it = 0; it < iters; ++it) {
        // ---- convert + store staged regs to LDS ----
        if (!TRANS) {
            const int row = tid >> 1, ho = (tid & 1) << 4;
            const float* f = (const float*)ra;
            short8 w0, w1;
#pragma unroll
            for (int j = 0; j < 8; ++j) { w0[j] = (short)f2bf(f[j]); w1[j] = (short)f2bf(f[8 + j]); }
            unsigned short* d = a_s + AROW(row) + ho;
            *(short8*)d = w0;
            *(short8*)(d + 8) = w1;
        } else {
            const int bm = tid & 31, bk = tid >> 5;
            const float* f = (const float*)ra;   // f[jk*4 + jm] = A[k+jk][m+jm]
#pragma unroll
            for (int jm = 0; jm < 4; ++jm) {
                short4v w = { (short)f2bf(f[jm]),     (short)f2bf(f[4 + jm]),
                              (short)f2bf(f[8 + jm]), (short)f2bf(f[12 + jm]) };
                *(short4v*)(a_s + AROW((bm << 2) + jm) + (bk << 2)) = w;
            }
        }
        {
            const int bd = tid & 15, bk2 = tid >> 4;
            const float* f = (const float*)rb;   // f[j*4 + jd] = B[k+j][d+jd]
#pragma unroll
            for (int jd = 0; jd < 4; ++jd) {
                short2v w = { (short)f2bf(f[jd]), (short)f2bf(f[4 + jd]) };
                *(short2v*)(b_s + AROW((bd << 2) + jd) + (bk2 << 1)) = w;
            }
        }
        __syncthreads();

        // ---- prefetch next iteration's globals (fly under the MFMA phase) ----
        if (it + 1 < iters) {
            if (!TRANS) {
                ap += 32;
#pragma unroll
                for (int j = 0; j < 4; ++j) ra[j] = ((const float4*)ap)[j];
            } else {
                ap += (size_t)32 * ldm;
#pragma unroll
                for (int j = 0; j < 4; ++j) ra[j] = *(const float4*)(ap + (size_t)j * ldm);
            }
            bp += 32 * 64;
            rb[0] = *(const float4*)bp;
            rb[1] = *(const float4*)(bp + 64);
        }

        // ---- MFMA: each wave computes 32 rows x 64 cols ----
        const int ko   = (lane >> 4) << 3;
        const int mrow = (wid << 5) + (lane & 15);
        short8 af0 = *(const short8*)(a_s + AROW(mrow) + ko);
        short8 af1 = *(const short8*)(a_s + AROW(mrow + 16) + ko);
#pragma unroll
        for (int nt = 0; nt < 4; ++nt) {
            short8 bf = *(const short8*)(b_s + AROW((nt << 4) + (lane & 15)) + ko);
            acc[0][nt] = __builtin_amdgcn_mfma_f32_16x16x32_bf16(af0, bf, acc[0][nt], 0, 0, 0);
            acc[1][nt] = __builtin_amdgcn_mfma_f32_16x16x32_bf16(af1, bf, acc[1][nt], 0, 0, 0);
        }
        __syncthreads();
    }

    // ---- epilogue: atomic accumulate (C pre-zeroed; split-K partial sums) ----
    const int col   = lane & 15;
    const int rbase = (lane >> 4) << 2;
#pragma unroll
    for (int mt = 0; mt < 2; ++mt)
#pragma unroll
        for (int nt = 0; nt < 4; ++nt)
#pragma unroll
            for (int i = 0; i < 4; ++i) {
                int row = m0 + (wid << 5) + (mt << 4) + rbase + i;
                atomicAdd(&Cp[((size_t)row << 6) + (nt << 4) + col], acc[mt][nt][i]);
            }
}

__device__ inline float wsum(float v) {
#pragma unroll
    for (int off = 32; off > 0; off >>= 1) v += __shfl_xor(v, off, 64);
    return v;
}

// One wave per user: Xu, cosine sims vs base, mask/var, user_embedding.
__global__ __launch_bounds__(256) void user_stats_k(
    const float* __restrict__ u0, const float* __restrict__ u1,
    const float* __restrict__ u2, const float* __restrict__ W,
    float* __restrict__ base_o, float* __restrict__ var_o, float* __restrict__ ue_o)
{
    int u    = blockIdx.x * 4 + (threadIdx.x >> 6);
    int lane = threadIdx.x & 63;
    size_t ud = ((size_t)u << 6) + lane;

    float b0 = u0[ud];
    float xu[5];
#pragma unroll
    for (int r = 0; r < 5; ++r)
        xu[r] = (b0 + u1[(size_t)r * U_DIM * 64 + ud] + u2[(size_t)r * U_DIM * 64 + ud]) * (1.0f / 3.0f);

    float base = xu[0];
    float n0 = sqrtf(wsum(base * base));
    float sim[4];
#pragma unroll
    for (int a = 0; a < 4; ++a) {
        float d  = wsum(base * xu[a + 1]);
        float nr = sqrtf(wsum(xu[a + 1] * xu[a + 1]));
        sim[a] = d / fmaxf(n0 * nr, EPSV);
    }
    float smax = fmaxf(fmaxf(sim[0], sim[1]), fmaxf(sim[2], sim[3]));
    float ssum = 0.0f;
    float simm[4];
#pragma unroll
    for (int a = 0; a < 4; ++a) { simm[a] = (sim[a] == smax) ? sim[a] : 0.0f; ssum += simm[a]; }
    float mean = ssum * 0.25f;
    float vs = 0.0f;
#pragma unroll
    for (int a = 0; a < 4; ++a) { float t = simm[a] - mean; vs += t * t; }
    vs *= (1.0f / 3.0f);
    float var = logf(sqrtf(vs) + 1.0f);

    float ue = 0.0f;
#pragma unroll
    for (int a = 0; a < 4; ++a) ue += W[((size_t)u << 2) + a] * xu[a + 1];

    base_o[ud] = base;
    ue_o[ud]   = ue;
    if (lane == 0) var_o[u] = var;
}

// One wave per batch element: X_post, X_var_user, AugUser, X_mean_user.
__global__ __launch_bounds__(256) void gather_k(
    const float* __restrict__ p0, const float* __restrict__ p1r0, const float* __restrict__ p2,
    const float* __restrict__ base, const float* __restrict__ var, const float* __restrict__ ue,
    const int* __restrict__ src_id, const int* __restrict__ rumer, float* __restrict__ out)
{
    int b    = blockIdx.x * 4 + (threadIdx.x >> 6);
    int lane = threadIdx.x & 63;

    int sp = src_id[b];
    size_t spd = ((size_t)sp << 6) + lane;
    out[((size_t)b << 6) + lane] = (p0[spd] + p1r0[spd] + p2[spd]) * (1.0f / 3.0f);

    float xv = 0.0f, xm = 0.0f, au = 0.0f;
    for (int h = 0; h < H_DIM; ++h) {
        int uu = rumer[b * H_DIM + h];
        size_t uud = ((size_t)uu << 6) + lane;
        float bv = base[uud];
        xv += var[uu] * bv;
        xm += bv;
        au += ue[uud];
    }
    out[((size_t)(B_DIM     + b) << 6) + lane] = xv;
    out[((size_t)(2 * B_DIM + b) << 6) + lane] = au * (1.0f / H_DIM);
    out[((size_t)(3 * B_DIM + b) << 6) + lane] = xm * (1.0f / H_DIM);
}

extern "C" void kernel_launch(void* const* d_in, const int* in_sizes, int n_in,
                              void* d_out, int out_size, void* d_ws, size_t ws_size,
                              hipStream_t stream)
{
    const float* u0 = (const float*)d_in[5];
    const float* p0 = (const float*)d_in[6];
    const float* W  = (const float*)d_in[7];
    const int* src   = (const int*)d_in[8];
    const int* rumer = (const int*)d_in[10];
    float* out = (float*)d_out;

    APtrs Ap;
    for (int r = 0; r < 5; ++r) Ap.p[r] = (const float*)d_in[r];

    // workspace layout (fp32)
    float* u1   = (float*)d_ws;                 // 5*U*64
    float* p1   = u1 + 5l * U_DIM * 64;         // 5*P*64
    float* p2   = p1 + 5l * P_DIM * 64;         // P*64
    float* u2   = p2 + (long)P_DIM * 64;        // 5*U*64
    float* base = u2 + 5l * U_DIM * 64;         // U*64
    float* var  = base + (long)U_DIM * 64;      // U
    float* ue   = var + U_DIM;                  // U*64

    size_t zero_bytes = (size_t)(5l * U_DIM * 64 + 5l * P_DIM * 64 + (long)P_DIM * 64 + 5l * U_DIM * 64) * sizeof(float);
    hipMemsetAsync(d_ws, 0, zero_bytes, stream);

    // u1[r] = A[r] @ p0          (K = P, contraction over columns)
    gemm_n64<false><<<dim3(64, 5, 4), 256, 0, stream>>>(Ap, p0, u1, P_DIM, 0, 0, (long)U_DIM * 64, 1024);
    // p1[r] = A[r]^T @ u0        (K = U, contraction over rows)
    gemm_n64<true ><<<dim3(32, 5, 8), 256, 0, stream>>>(Ap, u0, p1, U_DIM, P_DIM, 0, (long)P_DIM * 64, 1024);
    // u2[r] = A[r] @ p1[r]
    gemm_n64<false><<<dim3(64, 5, 4), 256, 0, stream>>>(Ap, p1, u2, P_DIM, 0, (long)P_DIM * 64, (long)U_DIM * 64, 1024);
    // p2[0] = A[0]^T @ u1[0]
    gemm_n64<true ><<<dim3(32, 1, 16), 256, 0, stream>>>(Ap, u1, p2, U_DIM, P_DIM, 0, 0, 512);

    user_stats_k<<<U_DIM / 4, 256, 0, stream>>>(u0, u1, u2, W, base, var, ue);
    gather_k<<<B_DIM / 4, 256, 0, stream>>>(p0, p1, p2, base, var, ue, src, rumer, out);
}